// Round 10
// baseline (231.533 us; speedup 1.0000x reference)
//
#include <hip/hip_runtime.h>

#define TN 16000

// ---------- radix chain: composite {16,20,25} + {8,10,4,2,5}; odd radices last ----------
constexpr int nrad(int L){
  return (L%16==0) ? 16 : (L==40) ? 8 : (L%20==0) ? 20 : (L%8==0) ? 8 :
         (L%10==0) ? 10 : (L%4==0) ? 4 : (L%2==0) ? 2 : (L%25==0) ? 25 : 5;
}

__device__ __forceinline__ float2 cmulf(float2 a, float2 b){
  return make_float2(a.x*b.x - a.y*b.y, a.x*b.y + a.y*b.x);
}
__device__ __forceinline__ float2 cadd(float2 a, float2 b){ return make_float2(a.x+b.x, a.y+b.y); }
__device__ __forceinline__ float2 csub(float2 a, float2 b){ return make_float2(a.x-b.x, a.y-b.y); }

template<int L>
__device__ __forceinline__ int f2p(int k){
  if constexpr (L == 1) return 0;
  else {
    constexpr int R = nrad(L);
    return (k % R) * (L / R) + f2p<L / R>(k / R);
  }
}
template<int L>
__device__ __forceinline__ int p2f(int p){
  if constexpr (L == 1) return 0;
  else {
    constexpr int R = nrad(L);
    const int hi = p / (L / R);
    const int lo = p - hi * (L / R);
    return hi + R * p2f<L / R>(lo);
  }
}

template<bool SWZ>
__device__ __forceinline__ int sx(int i){ return SWZ ? (i ^ ((i >> 7) & 7)) : i; }

// ---------- small DFT cores ----------
template<bool INV>
__device__ __forceinline__ void dft5c(float2* t){
  const float CR[5]={1.f,0.30901699437494742f,-0.80901699437494745f,
                     -0.80901699437494745f,0.30901699437494742f};
  const float CI[5]={0.f,-0.95105651629515357f,-0.58778525229247313f,
                     0.58778525229247313f,0.95105651629515357f};
  float2 y[5];
#pragma unroll
  for (int i=0;i<5;i++) y[i]=t[i];
#pragma unroll
  for (int u=0;u<5;u++){
    float zr=0.f, zi=0.f;
#pragma unroll
    for (int k=0;k<5;k++){
      const int m=(k*u)%5;
      const float wr=CR[m];
      const float wi=INV? -CI[m]:CI[m];
      zr += y[k].x*wr - y[k].y*wi;
      zi += y[k].x*wi + y[k].y*wr;
    }
    t[u]=make_float2(zr,zi);
  }
}

template<bool INV>
__device__ __forceinline__ void dft4c(float2* a){
  float2 s02=cadd(a[0],a[2]), d02=csub(a[0],a[2]);
  float2 s13=cadd(a[1],a[3]), d13=csub(a[1],a[3]);
  a[0]=cadd(s02,s13); a[2]=csub(s02,s13);
  if constexpr (INV){
    a[1]=make_float2(d02.x-d13.y, d02.y+d13.x);
    a[3]=make_float2(d02.x+d13.y, d02.y-d13.x);
  } else {
    a[1]=make_float2(d02.x+d13.y, d02.y-d13.x);
    a[3]=make_float2(d02.x-d13.y, d02.y+d13.x);
  }
}

template<bool INV>
__device__ __forceinline__ void dft8(float2* y){
  float2 e[4]={y[0],y[2],y[4],y[6]};
  float2 o[4]={y[1],y[3],y[5],y[7]};
  dft4c<INV>(e); dft4c<INV>(o);
  const float C=0.70710678118654752f;
  const float2 w1 = INV ? make_float2(C,C)   : make_float2(C,-C);
  const float2 w2 = INV ? make_float2(0.f,1.f): make_float2(0.f,-1.f);
  const float2 w3 = INV ? make_float2(-C,C)  : make_float2(-C,-C);
  float2 t;
  t=o[0];            y[0]=cadd(e[0],t); y[4]=csub(e[0],t);
  t=cmulf(o[1],w1);  y[1]=cadd(e[1],t); y[5]=csub(e[1],t);
  t=cmulf(o[2],w2);  y[2]=cadd(e[2],t); y[6]=csub(e[2],t);
  t=cmulf(o[3],w3);  y[3]=cadd(e[3],t); y[7]=csub(e[3],t);
}

template<bool INV>
__device__ __forceinline__ void dft10(float2* y){
  float2 e[5]={y[0],y[2],y[4],y[6],y[8]};
  float2 o[5]={y[1],y[3],y[5],y[7],y[9]};
  dft5c<INV>(e); dft5c<INV>(o);
  const float CR[5]={1.f,0.80901699437494745f,0.30901699437494742f,
                     -0.30901699437494742f,-0.80901699437494745f};
  const float SI[5]={0.f,0.58778525229247313f,0.95105651629515357f,
                     0.95105651629515357f,0.58778525229247313f};
#pragma unroll
  for (int u=0;u<5;u++){
    const float2 w = make_float2(CR[u], INV ? SI[u] : -SI[u]);
    const float2 t = cmulf(o[u], w);
    y[u]   = cadd(e[u], t);
    y[u+5] = csub(e[u], t);
  }
}

template<int R, bool INV>
__device__ __forceinline__ void dftR(float2* y){
  if constexpr (R==2){ float2 a=y[0],b=y[1]; y[0]=cadd(a,b); y[1]=csub(a,b); }
  else if constexpr (R==4){ dft4c<INV>(y); }
  else if constexpr (R==5){ dft5c<INV>(y); }
  else if constexpr (R==8){ dft8<INV>(y); }
  else { dft10<INV>(y); }
}

// ---------- constant twiddle tables for composite radices (W_NN^m) ----------
template<int NN, bool INV>
__device__ __forceinline__ float2 wNc(int m){
  if constexpr (NN==25){
    const float CR[17]={1.f,0.968583161f,0.876306680f,0.728968627f,0.535826795f,
                        0.309016994f,0.062790520f,-0.187381315f,-0.425779292f,
                        -0.637423990f,-0.809016994f,-0.929776486f,-0.992114701f,
                        -0.992114701f,-0.929776486f,-0.809016994f,-0.637423990f};
    const float SI[17]={0.f,0.248689887f,0.481753674f,0.684547106f,0.844327926f,
                        0.951056516f,0.998026728f,0.982287251f,0.904827052f,
                        0.770513243f,0.587785252f,0.368124553f,0.125333234f,
                        -0.125333234f,-0.368124553f,-0.587785252f,-0.770513243f};
    return make_float2(CR[m], INV ? SI[m] : -SI[m]);
  } else if constexpr (NN==20){
    const float CR[13]={1.f,0.951056516f,0.809016994f,0.587785252f,0.309016994f,
                        0.f,-0.309016994f,-0.587785252f,-0.809016994f,-0.951056516f,
                        -1.f,-0.951056516f,-0.809016994f};
    const float SI[13]={0.f,0.309016994f,0.587785252f,0.809016994f,0.951056516f,
                        1.f,0.951056516f,0.809016994f,0.587785252f,0.309016994f,
                        0.f,-0.309016994f,-0.587785252f};
    return make_float2(CR[m], INV ? SI[m] : -SI[m]);
  } else { // 16
    const float CR[10]={1.f,0.923879533f,0.707106781f,0.382683432f,0.f,
                        -0.382683432f,-0.707106781f,-0.923879533f,-1.f,-0.923879533f};
    const float SI[10]={0.f,0.382683432f,0.707106781f,0.923879533f,1.f,
                        0.923879533f,0.707106781f,0.382683432f,0.f,-0.382683432f};
    return make_float2(CR[m], INV ? SI[m] : -SI[m]);
  }
}

// register-resident 25-pt DFT (ONLY in k_split)
template<bool INV>
__device__ __forceinline__ void dft25(float2* y){
  float2 g[25];
#pragma unroll
  for (int a=0;a<5;a++){
    float2 t[5];
#pragma unroll
    for (int b=0;b<5;b++) t[b]=y[a+5*b];
    dft5c<INV>(t);
#pragma unroll
    for (int c=0;c<5;c++){
      float2 v=t[c];
      const int m=a*c;
      if (m) v=cmulf(v, wNc<25,INV>(m));
      g[a+5*c]=v;
    }
  }
#pragma unroll
  for (int c=0;c<5;c++){
    float2 t[5];
#pragma unroll
    for (int a=0;a<5;a++) t[a]=g[a+5*c];
    dft5c<INV>(t);
#pragma unroll
    for (int d=0;d<5;d++) y[c+5*d]=t[d];
  }
}

template<int R, bool INV>
__device__ __forceinline__ void twiddles(float2* y, int j, float invL){
  if (j == 0) return;
  const float ang = (INV ? 6.28318530717958647692f : -6.28318530717958647692f)
                    * (float)j * invL;
  float s,c; __sincosf(ang,&s,&c);
  const float2 w = make_float2(c,s);
  float2 wp = w;
  y[1]=cmulf(y[1],wp);
#pragma unroll
  for (int u=2;u<R;u++){ wp=cmulf(wp,w); y[u]=cmulf(y[u],wp); }
}

template<bool INV>
__device__ __forceinline__ void twiddles25(float2* y, int j, float invL){
  if (j == 0) return;
  const float ang = (INV ? 6.28318530717958647692f : -6.28318530717958647692f)
                    * (float)j * invL;
  float s,c; __sincosf(ang,&s,&c);
  const float2 w1=make_float2(c,s);
  __sincosf(5.f*ang,&s,&c);
  const float2 w5=make_float2(c,s);
  float2 Wb[5], Wa[5];
  Wb[1]=w1; Wb[2]=cmulf(w1,w1); Wb[3]=cmulf(Wb[2],w1); Wb[4]=cmulf(Wb[2],Wb[2]);
  Wa[1]=w5; Wa[2]=cmulf(w5,w5); Wa[3]=cmulf(Wa[2],w5); Wa[4]=cmulf(Wa[2],Wa[2]);
#pragma unroll
  for (int a=0;a<5;a++)
#pragma unroll
    for (int b=0;b<5;b++){
      const int u=5*a+b;
      if (u==0) continue;
      float2 v=y[u];
      if (a) v=cmulf(v,Wa[a]);
      if (b) v=cmulf(v,Wb[b]);
      y[u]=v;
    }
}

// ---------- small-radix LDS stage (R<=10) ----------
template<int N, int L, int R, bool INV, int EPI, bool SWZ>
__device__ void stageg(float2* buf, int tid, int nt, float esc){
  constexpr int M = L/R;
  constexpr float invL = 1.f/(float)L;
  for (int f = tid; f < N/R; f += nt){
    const int blk = f / M;
    const int j = f - blk*M;
    const int base = blk*L + j;
    float2 y[R];
#pragma unroll
    for (int t=0;t<R;t++) y[t]=buf[sx<SWZ>(base + t*M)];
    if constexpr (INV){
      twiddles<R,true>(y,j,invL);
      dftR<R,true>(y);
    } else {
      dftR<R,false>(y);
      twiddles<R,false>(y,j,invL);
    }
#pragma unroll
    for (int u=0;u<R;u++){
      if constexpr (EPI==1)
        buf[sx<SWZ>(base+u*M)]=make_float2(sqrtf(y[u].x*y[u].x+y[u].y*y[u].y)*esc, 0.f);
      else
        buf[sx<SWZ>(base+u*M)]=y[u];
    }
  }
}

// ---------- composite-radix stage R=R1*R2 (16/20/25), two register passes ----------
// DFT_R: t=a+R1*b, u=c+R2*d; W_R^{tu} = W_R^{ac} W_R1^{ad} W_R2^{bc}
template<int N, int L, int R1, int R2, bool INV, int EPI, bool SWZ>
__device__ void stageCT(float2* buf, int tid, int nt, float esc){
  constexpr int R = R1*R2;
  constexpr int M = L/R;
  constexpr float invL = 1.f/(float)L;
  for (int f = tid; f < N/R; f += nt){
    const int blk = f / M;
    const int j = f - blk*M;
    const int base = blk*L + j;
    float2 y[R];
    if constexpr (INV){
      // inverse: stage twiddle W_L^{+j*t} applied to inputs
      const float ang = 6.28318530717958647692f*(float)j*invL;
      float s,c; __sincosf(ang,&s,&c);
      const float2 w1 = make_float2(c,s);
      float2 pa[R1];
      pa[0]=make_float2(1.f,0.f);
#pragma unroll
      for (int a=1;a<R1;a++) pa[a]=cmulf(pa[a-1],w1);
      const float2 wR1 = cmulf(pa[R1-1], w1);
      float2 wb = make_float2(1.f,0.f);
#pragma unroll
      for (int b=0;b<R2;b++){
#pragma unroll
        for (int a=0;a<R1;a++){
          float2 v = buf[sx<SWZ>(base+(a+R1*b)*M)];
          y[a+R1*b] = cmulf(v, cmulf(pa[a], wb));
        }
        wb = cmulf(wb, wR1);
      }
    } else {
#pragma unroll
      for (int i=0;i<R;i++) y[i]=buf[sx<SWZ>(base+i*M)];
    }
    // pass 1: DFT-R2 over b (per a), then W_R^{ac}
#pragma unroll
    for (int a=0;a<R1;a++){
      float2 t[R2];
#pragma unroll
      for (int b=0;b<R2;b++) t[b]=y[a+R1*b];
      dftR<R2,INV>(t);
#pragma unroll
      for (int c=0;c<R2;c++){
        float2 v=t[c];
        if (a*c) v=cmulf(v, wNc<R,INV>(a*c));
        y[a+R1*c]=v;
      }
    }
    // pass 2: DFT-R1 over a (per c); u=c+R2*d; forward fuses W_L^{j*u}
    float2 w1 = make_float2(1.f,0.f);
    float2 pd[R1];
    if constexpr (!INV){
      const float ang = -6.28318530717958647692f*(float)j*invL;
      float s,c; __sincosf(ang,&s,&c);
      w1 = make_float2(c,s);
      float2 wr2 = w1;
#pragma unroll
      for (int q=1;q<R2;q++) wr2 = cmulf(wr2, w1);
      pd[0]=make_float2(1.f,0.f);
#pragma unroll
      for (int d=1;d<R1;d++) pd[d]=cmulf(pd[d-1],wr2);
    }
    float2 wc = make_float2(1.f,0.f);
#pragma unroll
    for (int c=0;c<R2;c++){
      float2 t[R1];
#pragma unroll
      for (int a=0;a<R1;a++) t[a]=y[a+R1*c];
      dftR<R1,INV>(t);
#pragma unroll
      for (int d=0;d<R1;d++){
        const int u=c+R2*d;
        float2 v=t[d];
        if constexpr (!INV) v = cmulf(v, cmulf(wc, pd[d]));
        if constexpr (EPI==1)
          buf[sx<SWZ>(base+u*M)]=make_float2(sqrtf(v.x*v.x+v.y*v.y)*esc, 0.f);
        else
          buf[sx<SWZ>(base+u*M)]=v;
      }
      if constexpr (!INV) wc = cmulf(wc, w1);
    }
  }
}

template<int N, int L, int R, bool INV, int EPI, bool SWZ>
__device__ __forceinline__ void stage_any(float2* buf, int tid, int nt, float esc){
  if constexpr (R >= 16){
    constexpr int R1 = (R==16)?4:5;
    constexpr int R2 = R/R1;
    stageCT<N,L,R1,R2,INV,EPI,SWZ>(buf,tid,nt,esc);
  } else {
    stageg<N,L,R,INV,EPI,SWZ>(buf,tid,nt,esc);
  }
}

template<int N, int L, bool SWZ>
__device__ void fwd_rec(float2* buf, int tid, int nt){
  if constexpr (L > 1){
    constexpr int R = nrad(L);
    stage_any<N,L,R,false,0,SWZ>(buf,tid,nt,0.f);
    __syncthreads();
    fwd_rec<N,L/R,SWZ>(buf,tid,nt);
  }
}
template<int N, int L, int EPI, bool SWZ>
__device__ void inv_rec(float2* buf, int tid, int nt, float esc){
  if constexpr (L > 1){
    constexpr int R = nrad(L);
    inv_rec<N,L/R,0,SWZ>(buf,tid,nt,0.f);
    stage_any<N,L,R,true,(L==N?EPI:0),SWZ>(buf,tid,nt,esc);
    __syncthreads();
  }
}

__device__ __forceinline__ float norm_val(float s){
  const float lt = log1pf(fabsf(s)*1.0e5f)*1.0e-5f;
  return 0.7f*s + 0.3f*copysignf(lt, s);
}

// ---------------- kernel 1a: radix-25 first DIF stage (20 blocks) + S0 (32 blocks) ----------------
__global__ __launch_bounds__(256) void k_split(const float* __restrict__ x,
                                               float2* __restrict__ Xmid,
                                               float* __restrict__ out){
  __shared__ float sseg[4384];
  __shared__ float stab[412];
  const int tid = threadIdx.x;
  if (blockIdx.x >= 20){
    const int s = blockIdx.x - 20;
    const int b = s >> 2;
    const int o0 = (s & 3) * 32;
    const float* xb = x + b*TN;
    const int n0 = o0*128 - 204;
    for (int i=tid;i<4377;i+=256){
      int n = n0 + i;
      n += (n < 0) ? TN : 0;
      n -= (n >= TN) ? TN : 0;
      const float c=__cosf((float)n*(6.28318530717958647692f/16000.0f));
      sseg[i]=xb[n]*(0.08f+0.46f*(1.0f-c));
    }
    for (int i=tid;i<409;i+=256){
      const float dd=(float)(i-204);
      stab[i]=0.0078332134f*__expf(-1.9276571e-4f*dd*dd);
    }
    __syncthreads();
    const int o=tid>>3, g=tid&7;
    float acc=0.f;
    for (int d=-204+g; d<=204; d+=8)
      acc += stab[d+204]*sseg[o*128 + 204 - d];
    acc += __shfl_xor(acc,1); acc += __shfl_xor(acc,2); acc += __shfl_xor(acc,4);
    if (g==0 && o0+o<125) out[(size_t)b*337*125 + o0+o]=norm_val(acc);
    return;
  }
  const int gid = blockIdx.x*256 + tid;
  const int b = gid/640, j = gid - (gid/640)*640;
  const float* xb = x + b*TN;
  float2 y[25];
#pragma unroll
  for (int t=0;t<25;t++){
    const int n=j+640*t;
    const float c=__cosf((float)n*(6.28318530717958647692f/16000.0f));
    y[t]=make_float2(xb[n]*(0.08f+0.46f*(1.0f-c)), 0.f);
  }
  dft25<false>(y);
  twiddles25<false>(y, j, 1.f/16000.f);
  float2* Xm = Xmid + (size_t)b*TN;
#pragma unroll
  for (int u=0;u<25;u++) Xm[u*640+j]=y[u];
}

// ---------------- kernel 1b: 25 independent 640-pt FFTs per batch ----------------
__global__ __launch_bounds__(256) void k_sub(const float2* __restrict__ Xmid,
                                             float2* __restrict__ Xnat){
  __shared__ float2 sb[640];
  const int tid=threadIdx.x;
  const int b=blockIdx.x/25, u0=blockIdx.x%25;
  const float2* src = Xmid + (size_t)b*TN + u0*640;
  for (int i=tid;i<640;i+=256) sb[i]=src[i];
  __syncthreads();
  fwd_rec<640,640,false>(sb,tid,256);
  float2* Xb = Xnat + (size_t)b*TN;
  for (int m=tid;m<640;m+=256) Xb[u0+25*m]=sb[f2p<640>(m)];
}

// ---------------- order-1 body: demodulated band-limited ----------------
template<int W, int NT>
__device__ void o1body(const float2* __restrict__ Xnat, float2* __restrict__ U1h,
                       float* __restrict__ out, int b, int p1, int tid,
                       float2* buf, float* htab, int store_n, int zero_to){
  constexpr float TAU = 16000.f/(float)W;
  constexpr int DMAX = (204*W + TN-1)/TN;
  constexpr int OSTEP = W/125;
  for (int i=tid; i<2*DMAX+1; i+=NT){
    const float dd = TAU*(float)(i-DMAX);
    htab[i]=0.0078332134f*__expf(-1.9276571e-4f*dd*dd);
  }
  const float xi = 0.5f*exp2f(-(float)(p1+1)*(1.0f/12.0f));
  const float sg = xi*0.11892618871859045f;
  const float niv = -1.f/(2.f*sg*sg);
  int k0 = (int)(16000.f*(xi+5.f*sg)) + 1 - W;
  if (k0 < 0) k0 = 0;
  const float2* Xb = Xnat + (size_t)b*TN;
  for (int p=tid;p<W;p+=NT){
    const int k = k0 + p2f<W>(p);
    const float d=(float)k*(1.f/16000.f)-xi;
    const float g=__expf(niv*d*d);
    const float2 v=Xb[k];
    buf[sx<true>(p)]=make_float2(v.x*g, v.y*g);
  }
  __syncthreads();
  inv_rec<W,W,1,true>(buf,tid,NT,1.f/16000.f);   // envelope in .x
  constexpr int G = (NT >= 1024) ? 8 : (NT >= 512) ? 4 : 1;
  {
    const int o = (G>1) ? (tid/G) : tid;
    const int g = (G>1) ? (tid%G) : 0;
    float acc=0.f;
    if (o<125){
      for (int d=-DMAX+g; d<=DMAX; d+=G){
        int ix=o*OSTEP-d;
        ix += (ix<0)?W:0; ix -= (ix>=W)?W:0;
        acc += htab[d+DMAX]*buf[sx<true>(ix)].x;
      }
    }
    if constexpr (G==8){ acc += __shfl_xor(acc,1); acc += __shfl_xor(acc,2); acc += __shfl_xor(acc,4); }
    else if constexpr (G==4){ acc += __shfl_xor(acc,1); acc += __shfl_xor(acc,2); }
    if (o<125 && g==0) out[((size_t)b*337+1+p1)*125+o]=norm_val(TAU*acc);
  }
  if (store_n>0){
    __syncthreads();
    fwd_rec<W,W,true>(buf,tid,NT);
    float2* Ub = U1h + (size_t)(b*84+p1)*8000;
    for (int k=tid;k<store_n;k+=NT){
      const float2 v=buf[sx<true>(f2p<W>(k))];
      Ub[k]=make_float2(TAU*v.x, TAU*v.y);
    }
    for (int k=store_n+tid;k<zero_to;k+=NT) Ub[k]=make_float2(0.f,0.f);
  }
}

// fused: all 7 octaves, big-first
__global__ __launch_bounds__(1024) void k_order1(const float2* __restrict__ Xnat,
                                                 float2* __restrict__ U1h,
                                                 float* __restrict__ out){
  __shared__ float2 buf[10000];
  __shared__ float htab[257];
  const int tid=threadIdx.x;
  const int a=blockIdx.x/96, r=blockIdx.x%96, b=r/12, idx=r%12;
  const int p1=a*12+idx;
  switch(a){
    case 0: o1body<10000,1024>(Xnat,U1h,out,b,p1,tid,buf,htab,8000,8000); break;
    case 1: o1body< 5000,1024>(Xnat,U1h,out,b,p1,tid,buf,htab,4000,4000); break;
    case 2: o1body< 2500,1024>(Xnat,U1h,out,b,p1,tid,buf,htab,2000,2000); break;
    case 3: o1body< 1250,1024>(Xnat,U1h,out,b,p1,tid,buf,htab,1000,1000); break;
    case 4: o1body<  625,1024>(Xnat,U1h,out,b,p1,tid,buf,htab, 625,1000); break;
    case 5: o1body<  500,1024>(Xnat,U1h,out,b,p1,tid,buf,htab, 500, 500); break;
    default: o1body< 250,1024>(Xnat,U1h,out,b,p1,tid,buf,htab,   0,   0); break;
  }
}

// ---------------- order-2 body ----------------
template<int N, int NT>
__device__ void o2body(const float2* __restrict__ U1h, float* __restrict__ out,
                       int b, int p1, int j2, int q, int tid,
                       float2* buf, float* htab){
  constexpr int R = TN/N;
  constexpr int CMAX = (204*N + TN-1)/TN;
  constexpr int OSTEP = 128/R;
  for (int i=tid; i<2*CMAX+1; i+=NT){
    const float dd = (float)((i-CMAX)*R);
    htab[i]=0.0078332134f*__expf(-1.9276571e-4f*dd*dd);
  }
  const float xi = 0.5f*exp2f(-(float)(j2+1));
  const float sg = 0.5f*xi;
  const float niv = -1.f/(2.f*sg*sg);
  const float2* Zb = U1h + (size_t)(b*84+p1)*8000;
  for (int p=tid;p<N;p+=NT){
    const int k = p2f<N>(p);
    const float d=(float)k*(1.f/16000.f)-xi;
    const float g=__expf(niv*d*d);
    const float2 v=Zb[k];
    buf[sx<true>(p)]=make_float2(v.x*g, v.y*g);
  }
  __syncthreads();
  inv_rec<N,N,1,true>(buf,tid,NT,1.f/16000.f);
  constexpr int G = (NT >= 512) ? 4 : 1;
  const int o = (G>1) ? (tid/G) : tid;
  const int g = (G>1) ? (tid%G) : 0;
  float acc=0.f;
  if (o<125){
    for (int c=-CMAX+g; c<=CMAX; c+=G){
      int ix=o*OSTEP-c;
      ix += (ix<0)?N:0; ix -= (ix>=N)?N:0;
      acc += htab[c+CMAX]*buf[sx<true>(ix)].x;
    }
  }
  if constexpr (G==4){ acc += __shfl_xor(acc,1); acc += __shfl_xor(acc,2); }
  if (o<125 && g==0) out[((size_t)b*337+85+q)*125+o]=norm_val((float)R*acc);
}

// fused: all 6 j2 bands, big-first; 64.8KB LDS -> 2 blocks/CU
__global__ __launch_bounds__(512,4) void k_order2(const float2* __restrict__ U1h,
                                                  float* __restrict__ out){
  __shared__ float2 buf[8000];
  __shared__ float htab[205];
  const int tid=threadIdx.x;
  int id=blockIdx.x;
  int j2;
  if      (id<  96){ j2=1; }
  else if (id< 288){ j2=2; id-=  96; }
  else if (id< 576){ j2=3; id-= 288; }
  else if (id< 960){ j2=4; id-= 576; }
  else if (id<1440){ j2=5; id-= 960; }
  else             { j2=6; id-=1440; }
  const int npath=12*j2;
  const int b=id/npath, p1=id%npath;
  const int a=p1/12, rr=p1%12;
  const int q=12*(6*a-(a*(a-1))/2)+rr*(6-a)+(j2-a-1);
  switch(j2){
    case 1: o2body<8000,512>(U1h,out,b,p1,1,q,tid,buf,htab); break;
    case 2: o2body<4000,512>(U1h,out,b,p1,2,q,tid,buf,htab); break;
    case 3: o2body<2000,512>(U1h,out,b,p1,3,q,tid,buf,htab); break;
    case 4: o2body<1000,512>(U1h,out,b,p1,4,q,tid,buf,htab); break;
    case 5: o2body<1000,512>(U1h,out,b,p1,5,q,tid,buf,htab); break;
    default: o2body<500,512>(U1h,out,b,p1,6,q,tid,buf,htab); break;
  }
}

extern "C" void kernel_launch(void* const* d_in, const int* in_sizes, int n_in,
                              void* d_out, int out_size, void* d_ws, size_t ws_size,
                              hipStream_t stream){
  (void)in_sizes; (void)n_in; (void)out_size; (void)ws_size;
  const float* x = (const float*)d_in[0];
  float* out = (float*)d_out;
  float2* Xmid = (float2*)d_ws;                                          // 1 MB
  float2* Xnat = (float2*)((char*)d_ws + (size_t)8*TN*sizeof(float2));   // 1 MB
  float2* U1h  = (float2*)((char*)d_ws + (size_t)16*TN*sizeof(float2));  // 43 MB
  k_split <<<52,   256, 0, stream>>>(x, Xmid, out);
  k_sub   <<<200,  256, 0, stream>>>(Xmid, Xnat);
  k_order1<<<672, 1024, 0, stream>>>(Xnat, U1h, out);
  k_order2<<<2016, 512, 0, stream>>>(U1h, out);
}

// Round 11
// 92.812 us; speedup vs baseline: 2.4947x; 2.4947x over previous
//
#include <hip/hip_runtime.h>

#define TN 16000

// ---------- radix chain: {10 while 10|L, 5, 8 (not 16), 4, 2} (round-6/9 verified) ----------
constexpr int nrad(int L){
  return (L%10==0) ? 10 : (L%5==0) ? 5 : (L>=8 && L!=16) ? 8 : (L>=4) ? 4 : 2;
}

__device__ __forceinline__ float2 cmulf(float2 a, float2 b){
  return make_float2(a.x*b.x - a.y*b.y, a.x*b.y + a.y*b.x);
}
__device__ __forceinline__ float2 cadd(float2 a, float2 b){ return make_float2(a.x+b.x, a.y+b.y); }
__device__ __forceinline__ float2 csub(float2 a, float2 b){ return make_float2(a.x-b.x, a.y-b.y); }

// frequency k -> DIF output position
template<int L>
__device__ __forceinline__ int f2p(int k){
  if constexpr (L == 1) return 0;
  else {
    constexpr int R = nrad(L);
    return (k % R) * (L / R) + f2p<L / R>(k / R);
  }
}
// DIF output position p -> frequency k (inverse of f2p)
template<int L>
__device__ __forceinline__ int p2f(int p){
  if constexpr (L == 1) return 0;
  else {
    constexpr int R = nrad(L);
    const int hi = p / (L / R);
    const int lo = p - hi * (L / R);
    return hi + R * p2f<L / R>(lo);
  }
}

// LDS bank swizzle (bijective; buffers padded to cover image)
template<bool SWZ>
__device__ __forceinline__ int sx(int i){ return SWZ ? (i ^ ((i >> 7) & 7)) : i; }

// ---------- small DFT cores ----------
template<bool INV>
__device__ __forceinline__ void dft5c(float2* t){
  const float CR[5]={1.f,0.30901699437494742f,-0.80901699437494745f,
                     -0.80901699437494745f,0.30901699437494742f};
  const float CI[5]={0.f,-0.95105651629515357f,-0.58778525229247313f,
                     0.58778525229247313f,0.95105651629515357f};
  float2 y[5];
#pragma unroll
  for (int i=0;i<5;i++) y[i]=t[i];
#pragma unroll
  for (int u=0;u<5;u++){
    float zr=0.f, zi=0.f;
#pragma unroll
    for (int k=0;k<5;k++){
      const int m=(k*u)%5;
      const float wr=CR[m];
      const float wi=INV? -CI[m]:CI[m];
      zr += y[k].x*wr - y[k].y*wi;
      zi += y[k].x*wi + y[k].y*wr;
    }
    t[u]=make_float2(zr,zi);
  }
}

template<bool INV>
__device__ __forceinline__ void dft4c(float2* a){
  float2 s02=cadd(a[0],a[2]), d02=csub(a[0],a[2]);
  float2 s13=cadd(a[1],a[3]), d13=csub(a[1],a[3]);
  a[0]=cadd(s02,s13); a[2]=csub(s02,s13);
  if constexpr (INV){
    a[1]=make_float2(d02.x-d13.y, d02.y+d13.x);
    a[3]=make_float2(d02.x+d13.y, d02.y-d13.x);
  } else {
    a[1]=make_float2(d02.x+d13.y, d02.y-d13.x);
    a[3]=make_float2(d02.x-d13.y, d02.y+d13.x);
  }
}

template<bool INV>
__device__ __forceinline__ void dft8(float2* y){
  float2 e[4]={y[0],y[2],y[4],y[6]};
  float2 o[4]={y[1],y[3],y[5],y[7]};
  dft4c<INV>(e); dft4c<INV>(o);
  const float C=0.70710678118654752f;
  const float2 w1 = INV ? make_float2(C,C)   : make_float2(C,-C);
  const float2 w2 = INV ? make_float2(0.f,1.f): make_float2(0.f,-1.f);
  const float2 w3 = INV ? make_float2(-C,C)  : make_float2(-C,-C);
  float2 t;
  t=o[0];            y[0]=cadd(e[0],t); y[4]=csub(e[0],t);
  t=cmulf(o[1],w1);  y[1]=cadd(e[1],t); y[5]=csub(e[1],t);
  t=cmulf(o[2],w2);  y[2]=cadd(e[2],t); y[6]=csub(e[2],t);
  t=cmulf(o[3],w3);  y[3]=cadd(e[3],t); y[7]=csub(e[3],t);
}

template<bool INV>
__device__ __forceinline__ void dft10(float2* y){
  float2 e[5]={y[0],y[2],y[4],y[6],y[8]};
  float2 o[5]={y[1],y[3],y[5],y[7],y[9]};
  dft5c<INV>(e); dft5c<INV>(o);
  const float CR[5]={1.f,0.80901699437494745f,0.30901699437494742f,
                     -0.30901699437494742f,-0.80901699437494745f};
  const float SI[5]={0.f,0.58778525229247313f,0.95105651629515357f,
                     0.95105651629515357f,0.58778525229247313f};
#pragma unroll
  for (int u=0;u<5;u++){
    const float2 w = make_float2(CR[u], INV ? SI[u] : -SI[u]);
    const float2 t = cmulf(o[u], w);
    y[u]   = cadd(e[u], t);
    y[u+5] = csub(e[u], t);
  }
}

template<bool INV>
__device__ __forceinline__ float2 w25c(int m){
  const float CR[17]={1.f,0.968583161f,0.876306680f,0.728968627f,0.535826795f,
                      0.309016994f,0.062790520f,-0.187381315f,-0.425779292f,
                      -0.637423990f,-0.809016994f,-0.929776486f,-0.992114701f,
                      -0.992114701f,-0.929776486f,-0.809016994f,-0.637423990f};
  const float SI[17]={0.f,0.248689887f,0.481753674f,0.684547106f,0.844327926f,
                      0.951056516f,0.998026728f,0.982287251f,0.904827052f,
                      0.770513243f,0.587785252f,0.368124553f,0.125333234f,
                      -0.125333234f,-0.368124553f,-0.587785252f,-0.770513243f};
  return make_float2(CR[m], INV ? SI[m] : -SI[m]);
}

// register-resident 25-pt DFT (ONLY in k_split: 256-thr block, no VGPR cap issue)
template<bool INV>
__device__ __forceinline__ void dft25(float2* y){
  float2 g[25];
#pragma unroll
  for (int a=0;a<5;a++){
    float2 t[5];
#pragma unroll
    for (int b=0;b<5;b++) t[b]=y[a+5*b];
    dft5c<INV>(t);
#pragma unroll
    for (int c=0;c<5;c++){
      float2 v=t[c];
      const int m=a*c;
      if (m) v=cmulf(v, w25c<INV>(m));
      g[a+5*c]=v;
    }
  }
#pragma unroll
  for (int c=0;c<5;c++){
    float2 t[5];
#pragma unroll
    for (int a=0;a<5;a++) t[a]=g[a+5*c];
    dft5c<INV>(t);
#pragma unroll
    for (int d=0;d<5;d++) y[c+5*d]=t[d];
  }
}

template<int R, bool INV>
__device__ __forceinline__ void dftR(float2* y){
  if constexpr (R==2){ float2 a=y[0],b=y[1]; y[0]=cadd(a,b); y[1]=csub(a,b); }
  else if constexpr (R==4){ dft4c<INV>(y); }
  else if constexpr (R==5){ dft5c<INV>(y); }
  else if constexpr (R==8){ dft8<INV>(y); }
  else { dft10<INV>(y); }
}

template<int R, bool INV>
__device__ __forceinline__ void twiddles(float2* y, int j, float invL){
  if (j == 0) return;
  const float ang = (INV ? 6.28318530717958647692f : -6.28318530717958647692f)
                    * (float)j * invL;
  float s,c; __sincosf(ang,&s,&c);
  const float2 w = make_float2(c,s);
  float2 wp = w;
  y[1]=cmulf(y[1],wp);
#pragma unroll
  for (int u=2;u<R;u++){ wp=cmulf(wp,w); y[u]=cmulf(y[u],wp); }
}

template<bool INV>
__device__ __forceinline__ void twiddles25(float2* y, int j, float invL){
  if (j == 0) return;
  const float ang = (INV ? 6.28318530717958647692f : -6.28318530717958647692f)
                    * (float)j * invL;
  float s,c; __sincosf(ang,&s,&c);
  const float2 w1=make_float2(c,s);
  __sincosf(5.f*ang,&s,&c);
  const float2 w5=make_float2(c,s);
  float2 Wb[5], Wa[5];
  Wb[1]=w1; Wb[2]=cmulf(w1,w1); Wb[3]=cmulf(Wb[2],w1); Wb[4]=cmulf(Wb[2],Wb[2]);
  Wa[1]=w5; Wa[2]=cmulf(w5,w5); Wa[3]=cmulf(Wa[2],w5); Wa[4]=cmulf(Wa[2],Wa[2]);
#pragma unroll
  for (int a=0;a<5;a++)
#pragma unroll
    for (int b=0;b<5;b++){
      const int u=5*a+b;
      if (u==0) continue;
      float2 v=y[u];
      if (a) v=cmulf(v,Wa[a]);
      if (b) v=cmulf(v,Wb[b]);
      y[u]=v;
    }
}

// ---------- generic LDS stage; EPI==1 writes |z|*esc into .x ----------
template<int N, int L, int R, bool INV, int EPI, bool SWZ>
__device__ void stageg(float2* buf, int tid, int nt, float esc){
  constexpr int M = L/R;
  constexpr float invL = 1.f/(float)L;
  for (int f = tid; f < N/R; f += nt){
    const int blk = f / M;
    const int j = f - blk*M;
    const int base = blk*L + j;
    float2 y[R];
#pragma unroll
    for (int t=0;t<R;t++) y[t]=buf[sx<SWZ>(base + t*M)];
    if constexpr (INV){
      twiddles<R,true>(y,j,invL);
      dftR<R,true>(y);
    } else {
      dftR<R,false>(y);
      twiddles<R,false>(y,j,invL);
    }
#pragma unroll
    for (int u=0;u<R;u++){
      if constexpr (EPI==1)
        buf[sx<SWZ>(base+u*M)]=make_float2(sqrtf(y[u].x*y[u].x+y[u].y*y[u].y)*esc, 0.f);
      else
        buf[sx<SWZ>(base+u*M)]=y[u];
    }
  }
}

template<int N, int L, bool SWZ>
__device__ void fwd_rec(float2* buf, int tid, int nt){
  if constexpr (L > 1){
    constexpr int R = nrad(L);
    stageg<N,L,R,false,0,SWZ>(buf,tid,nt,0.f);
    __syncthreads();
    fwd_rec<N,L/R,SWZ>(buf,tid,nt);
  }
}
template<int N, int L, int EPI, bool SWZ>
__device__ void inv_rec(float2* buf, int tid, int nt, float esc){
  if constexpr (L > 1){
    constexpr int R = nrad(L);
    inv_rec<N,L/R,0,SWZ>(buf,tid,nt,0.f);
    stageg<N,L,R,true,(L==N?EPI:0),SWZ>(buf,tid,nt,esc);
    __syncthreads();
  }
}

__device__ __forceinline__ float norm_val(float s){
  const float lt = log1pf(fabsf(s)*1.0e5f)*1.0e-5f;
  return 0.7f*s + 0.3f*copysignf(lt, s);
}

// ---------------- kernel 1a: radix-25 first DIF stage (20 blocks) + S0 (32 blocks) ----------------
__global__ __launch_bounds__(256) void k_split(const float* __restrict__ x,
                                               float2* __restrict__ Xmid,
                                               float* __restrict__ out){
  __shared__ float sseg[4384];
  __shared__ float stab[412];
  const int tid = threadIdx.x;
  if (blockIdx.x >= 20){
    const int s = blockIdx.x - 20;
    const int b = s >> 2;
    const int o0 = (s & 3) * 32;
    const float* xb = x + b*TN;
    const int n0 = o0*128 - 204;
    for (int i=tid;i<4377;i+=256){
      int n = n0 + i;
      n += (n < 0) ? TN : 0;
      n -= (n >= TN) ? TN : 0;
      const float c=__cosf((float)n*(6.28318530717958647692f/16000.0f));
      sseg[i]=xb[n]*(0.08f+0.46f*(1.0f-c));
    }
    for (int i=tid;i<409;i+=256){
      const float dd=(float)(i-204);
      stab[i]=0.0078332134f*__expf(-1.9276571e-4f*dd*dd);
    }
    __syncthreads();
    const int o=tid>>3, g=tid&7;
    float acc=0.f;
    for (int d=-204+g; d<=204; d+=8)
      acc += stab[d+204]*sseg[o*128 + 204 - d];
    acc += __shfl_xor(acc,1); acc += __shfl_xor(acc,2); acc += __shfl_xor(acc,4);
    if (g==0 && o0+o<125) out[(size_t)b*337*125 + o0+o]=norm_val(acc);
    return;
  }
  const int gid = blockIdx.x*256 + tid;
  const int b = gid/640, j = gid - (gid/640)*640;
  const float* xb = x + b*TN;
  float2 y[25];
#pragma unroll
  for (int t=0;t<25;t++){
    const int n=j+640*t;
    const float c=__cosf((float)n*(6.28318530717958647692f/16000.0f));
    y[t]=make_float2(xb[n]*(0.08f+0.46f*(1.0f-c)), 0.f);
  }
  dft25<false>(y);
  twiddles25<false>(y, j, 1.f/16000.f);
  float2* Xm = Xmid + (size_t)b*TN;
#pragma unroll
  for (int u=0;u<25;u++) Xm[u*640+j]=y[u];
}

// ---------------- kernel 1b: 25 independent 640-pt FFTs per batch ----------------
__global__ __launch_bounds__(128) void k_sub(const float2* __restrict__ Xmid,
                                             float2* __restrict__ Xnat){
  __shared__ float2 sb[640];
  const int tid=threadIdx.x;
  const int b=blockIdx.x/25, u0=blockIdx.x%25;
  const float2* src = Xmid + (size_t)b*TN + u0*640;
  for (int i=tid;i<640;i+=128) sb[i]=src[i];
  __syncthreads();
  fwd_rec<640,640,false>(sb,tid,128);
  float2* Xb = Xnat + (size_t)b*TN;
  for (int m=tid;m<640;m+=128) Xb[u0+25*m]=sb[f2p<640>(m)];
}

// ---------------- order-1 body: demodulated band-limited (round-9 verified math) ----------------
template<int W, int NT>
__device__ void o1body(const float2* __restrict__ Xnat, float2* __restrict__ U1h,
                       float* __restrict__ out, int b, int p1, int tid,
                       float2* buf, float* htab, int store_n, int zero_to){
  constexpr float TAU = 16000.f/(float)W;
  constexpr int DMAX = (204*W + TN-1)/TN;
  constexpr int OSTEP = W/125;
  for (int i=tid; i<2*DMAX+1; i+=NT){
    const float dd = TAU*(float)(i-DMAX);
    htab[i]=0.0078332134f*__expf(-1.9276571e-4f*dd*dd);
  }
  const float xi = 0.5f*exp2f(-(float)(p1+1)*(1.0f/12.0f));
  const float sg = xi*0.11892618871859045f;
  const float niv = -1.f/(2.f*sg*sg);
  int k0 = (int)(16000.f*(xi+5.f*sg)) + 1 - W;
  if (k0 < 0) k0 = 0;
  const float2* Xb = Xnat + (size_t)b*TN;
  for (int p=tid;p<W;p+=NT){
    const int k = k0 + p2f<W>(p);
    const float d=(float)k*(1.f/16000.f)-xi;
    const float g=__expf(niv*d*d);
    const float2 v=Xb[k];
    buf[sx<true>(p)]=make_float2(v.x*g, v.y*g);
  }
  __syncthreads();
  inv_rec<W,W,1,true>(buf,tid,NT,1.f/16000.f);   // envelope in .x (natural time)
  constexpr int G = (NT >= 1024) ? 8 : (NT >= 512) ? 4 : 1;
  {
    const int o = (G>1) ? (tid/G) : tid;
    const int g = (G>1) ? (tid%G) : 0;
    float acc=0.f;
    if (o<125){
      for (int d=-DMAX+g; d<=DMAX; d+=G){
        int ix=o*OSTEP-d;
        ix += (ix<0)?W:0; ix -= (ix>=W)?W:0;
        acc += htab[d+DMAX]*buf[sx<true>(ix)].x;
      }
    }
    if constexpr (G==8){ acc += __shfl_xor(acc,1); acc += __shfl_xor(acc,2); acc += __shfl_xor(acc,4); }
    else if constexpr (G==4){ acc += __shfl_xor(acc,1); acc += __shfl_xor(acc,2); }
    if (o<125 && g==0) out[((size_t)b*337+1+p1)*125+o]=norm_val(TAU*acc);
  }
  if (store_n>0){
    __syncthreads();
    fwd_rec<W,W,true>(buf,tid,NT);
    float2* Ub = U1h + (size_t)(b*84+p1)*8000;
    for (int k=tid;k<store_n;k+=NT){
      const float2 v=buf[sx<true>(f2p<W>(k))];
      Ub[k]=make_float2(TAU*v.x, TAU*v.y);
    }
    for (int k=store_n+tid;k<zero_to;k+=NT) Ub[k]=make_float2(0.f,0.f);
  }
}

// fused: all 7 octaves in one dispatch, big octaves first (small blocks backfill)
__global__ __launch_bounds__(1024) void k_order1(const float2* __restrict__ Xnat,
                                                 float2* __restrict__ U1h,
                                                 float* __restrict__ out){
  __shared__ float2 buf[10000];
  __shared__ float htab[257];
  const int tid=threadIdx.x;
  const int a=blockIdx.x/96, r=blockIdx.x%96, b=r/12, idx=r%12;
  const int p1=a*12+idx;
  switch(a){
    case 0: o1body<10000,1024>(Xnat,U1h,out,b,p1,tid,buf,htab,8000,8000); break;
    case 1: o1body< 5000,1024>(Xnat,U1h,out,b,p1,tid,buf,htab,4000,4000); break;
    case 2: o1body< 2500,1024>(Xnat,U1h,out,b,p1,tid,buf,htab,2000,2000); break;
    case 3: o1body< 1250,1024>(Xnat,U1h,out,b,p1,tid,buf,htab,1000,1000); break;
    case 4: o1body<  625,1024>(Xnat,U1h,out,b,p1,tid,buf,htab, 625,1000); break;
    case 5: o1body<  500,1024>(Xnat,U1h,out,b,p1,tid,buf,htab, 500, 500); break;
    default: o1body< 250,1024>(Xnat,U1h,out,b,p1,tid,buf,htab,   0,   0); break;
  }
}

// ---------------- order-2 body (round-9 verified math) ----------------
template<int N, int NT>
__device__ void o2body(const float2* __restrict__ U1h, float* __restrict__ out,
                       int b, int p1, int j2, int q, int tid,
                       float2* buf, float* htab){
  constexpr int R = TN/N;
  constexpr int CMAX = (204*N + TN-1)/TN;
  constexpr int OSTEP = 128/R;
  for (int i=tid; i<2*CMAX+1; i+=NT){
    const float dd = (float)((i-CMAX)*R);
    htab[i]=0.0078332134f*__expf(-1.9276571e-4f*dd*dd);
  }
  const float xi = 0.5f*exp2f(-(float)(j2+1));
  const float sg = 0.5f*xi;
  const float niv = -1.f/(2.f*sg*sg);
  const float2* Zb = U1h + (size_t)(b*84+p1)*8000;
  for (int p=tid;p<N;p+=NT){
    const int k = p2f<N>(p);
    const float d=(float)k*(1.f/16000.f)-xi;
    const float g=__expf(niv*d*d);
    const float2 v=Zb[k];
    buf[sx<true>(p)]=make_float2(v.x*g, v.y*g);
  }
  __syncthreads();
  inv_rec<N,N,1,true>(buf,tid,NT,1.f/16000.f);
  constexpr int G = (NT >= 512) ? 4 : 1;
  const int o = (G>1) ? (tid/G) : tid;
  const int g = (G>1) ? (tid%G) : 0;
  float acc=0.f;
  if (o<125){
    for (int c=-CMAX+g; c<=CMAX; c+=G){
      int ix=o*OSTEP-c;
      ix += (ix<0)?N:0; ix -= (ix>=N)?N:0;
      acc += htab[c+CMAX]*buf[sx<true>(ix)].x;
    }
  }
  if constexpr (G==4){ acc += __shfl_xor(acc,1); acc += __shfl_xor(acc,2); }
  if (o<125 && g==0) out[((size_t)b*337+85+q)*125+o]=norm_val((float)R*acc);
}

// fused: all 6 j2 bands in one dispatch, big-first; 64.8KB LDS -> 2 blocks/CU
__global__ __launch_bounds__(512,4) void k_order2(const float2* __restrict__ U1h,
                                                  float* __restrict__ out){
  __shared__ float2 buf[8000];
  __shared__ float htab[205];
  const int tid=threadIdx.x;
  int id=blockIdx.x;
  int j2;
  if      (id<  96){ j2=1; }
  else if (id< 288){ j2=2; id-=  96; }
  else if (id< 576){ j2=3; id-= 288; }
  else if (id< 960){ j2=4; id-= 576; }
  else if (id<1440){ j2=5; id-= 960; }
  else             { j2=6; id-=1440; }
  const int npath=12*j2;
  const int b=id/npath, p1=id%npath;
  const int a=p1/12, rr=p1%12;
  const int q=12*(6*a-(a*(a-1))/2)+rr*(6-a)+(j2-a-1);
  switch(j2){
    case 1: o2body<8000,512>(U1h,out,b,p1,1,q,tid,buf,htab); break;
    case 2: o2body<4000,512>(U1h,out,b,p1,2,q,tid,buf,htab); break;
    case 3: o2body<2000,512>(U1h,out,b,p1,3,q,tid,buf,htab); break;
    case 4: o2body<1000,512>(U1h,out,b,p1,4,q,tid,buf,htab); break;
    case 5: o2body<1000,512>(U1h,out,b,p1,5,q,tid,buf,htab); break;
    default: o2body<500,512>(U1h,out,b,p1,6,q,tid,buf,htab); break;
  }
}

extern "C" void kernel_launch(void* const* d_in, const int* in_sizes, int n_in,
                              void* d_out, int out_size, void* d_ws, size_t ws_size,
                              hipStream_t stream){
  (void)in_sizes; (void)n_in; (void)out_size; (void)ws_size;
  const float* x = (const float*)d_in[0];
  float* out = (float*)d_out;
  float2* Xmid = (float2*)d_ws;                                          // 1 MB
  float2* Xnat = (float2*)((char*)d_ws + (size_t)8*TN*sizeof(float2));   // 1 MB
  float2* U1h  = (float2*)((char*)d_ws + (size_t)16*TN*sizeof(float2));  // 43 MB
  k_split <<<52,   256, 0, stream>>>(x, Xmid, out);
  k_sub   <<<200,  128, 0, stream>>>(Xmid, Xnat);
  k_order1<<<672, 1024, 0, stream>>>(Xnat, U1h, out);
  k_order2<<<2016, 512, 0, stream>>>(U1h, out);
}